// Round 4
// baseline (720.387 us; speedup 1.0000x reference)
//
#include <hip/hip_runtime.h>
#include <math.h>

#define G 8
#define T 4096
#define H 1024
#define E 32
#define C 64
#define NTOK (G*T)                     // 32768 tokens
#define COMBINE_SZ ((size_t)G*T*E*C)   // 67108864 floats
#define KC 64                          // h-chunk size
#define TBLK 128                       // tokens per block (2 per lane)

// ---------------------------------------------------------------------------
// Kernel 0 (R11): zero-fill combine+dispatch (536,870,912 B) + z_loss scalar.
// R3 forensics: our 536,870,916-byte hipMemsetAsync ran at only ~1.5-2 TB/s
// (>=254us by subtraction; R2 top-5 proves scalar-router <335us so the
// memset must be the slow term), while fillBufferAligned on 2.147GB hits
// 6.2 TB/s.  A plain grid-stride float4 store kernel pins us to the fast
// path: 2048 blocks x 256 thr x 64 float4 each, sequential addresses.
// ---------------------------------------------------------------------------
__global__ __launch_bounds__(256) void k_zero(float* __restrict__ out)
{
    const size_t N4     = (2 * COMBINE_SZ) / 4;          // 33,554,432 float4
    const size_t stride = (size_t)gridDim.x * 256;
    size_t i = (size_t)blockIdx.x * 256 + threadIdx.x;
    const float4 z4 = make_float4(0.f, 0.f, 0.f, 0.f);
    float4* __restrict__ o4 = (float4*)out;
    for (; i < N4; i += stride) o4[i] = z4;
    if (i == stride * ((N4 + stride - 1) / stride) - stride + (size_t)blockIdx.x * 256 + threadIdx.x) {}
    if (blockIdx.x == 0 && threadIdx.x == 0) out[2 * COMBINE_SZ] = 0.f;  // z_loss
}

// ---------------------------------------------------------------------------
// Kernel 1: router logits GEMM (fp32 vector) + softmax + z-loss + transposed
// probs store.  VERBATIM R7 (proven ~115us): LDS-staged W+x, 2 tokens/lane x
// 8 experts/wave.
// ---------------------------------------------------------------------------
__global__ __launch_bounds__(256) void k_router(
    const float* __restrict__ x, const float* __restrict__ W,
    const float* __restrict__ bias, float* __restrict__ probs_t,
    float* __restrict__ z_out)
{
    __shared__ float xs[TBLK][68];  // 34.8 KB; row stride 68 floats (16B-aligned)
    __shared__ float ws2[KC][32];   // 8 KB
    __shared__ float lt[TBLK][33];  // 16.9 KB  (total 59.9 KB)

    const int tid  = threadIdx.x;
    const int lane = tid & 63;
    const int wv   = __builtin_amdgcn_readfirstlane(tid >> 6);
    const int blk  = blockIdx.x;

    float acc0[8] = {0,0,0,0,0,0,0,0};   // token = blk*128 + lane
    float acc1[8] = {0,0,0,0,0,0,0,0};   // token = blk*128 + 64 + lane

    for (int ch = 0; ch < H / KC; ++ch) {
        const int h0 = ch * KC;

        // --- W chunk: 64 h x 32 e = 8 KB, contiguous, coalesced
        {
            const float4* __restrict__ src = (const float4*)(W + (size_t)h0 * E);
            float4* __restrict__ dst = (float4*)ws2;
            dst[tid]       = src[tid];
            dst[tid + 256] = src[tid + 256];
        }
        // --- x tile: 128 tok x 64 h; f -> tok=f>>4, h4=f&15
        #pragma unroll
        for (int k = 0; k < 8; ++k) {
            const int f   = k * 256 + tid;
            const int tok = f >> 4;
            const int h4  = f & 15;
            const float4 v = *(const float4*)(x + (size_t)(blk * TBLK + tok) * H + h0 + h4 * 4);
            *(float4*)(&xs[tok][h4 * 4]) = v;
        }
        __syncthreads();

        // --- compute: 2 tokens/lane x 8 experts
        for (int hh = 0; hh < KC; hh += 4) {
            const float4 xa = *(const float4*)(&xs[lane][hh]);
            const float4 xb = *(const float4*)(&xs[64 + lane][hh]);
            #pragma unroll
            for (int j = 0; j < 4; ++j) {
                const float4 w0 = *(const float4*)(&ws2[hh + j][wv * 8]);
                const float4 w1 = *(const float4*)(&ws2[hh + j][wv * 8 + 4]);
                const float a_ = (j == 0) ? xa.x : (j == 1) ? xa.y : (j == 2) ? xa.z : xa.w;
                const float b_ = (j == 0) ? xb.x : (j == 1) ? xb.y : (j == 2) ? xb.z : xb.w;
                acc0[0] = fmaf(a_, w0.x, acc0[0]);  acc1[0] = fmaf(b_, w0.x, acc1[0]);
                acc0[1] = fmaf(a_, w0.y, acc0[1]);  acc1[1] = fmaf(b_, w0.y, acc1[1]);
                acc0[2] = fmaf(a_, w0.z, acc0[2]);  acc1[2] = fmaf(b_, w0.z, acc1[2]);
                acc0[3] = fmaf(a_, w0.w, acc0[3]);  acc1[3] = fmaf(b_, w0.w, acc1[3]);
                acc0[4] = fmaf(a_, w1.x, acc0[4]);  acc1[4] = fmaf(b_, w1.x, acc1[4]);
                acc0[5] = fmaf(a_, w1.y, acc0[5]);  acc1[5] = fmaf(b_, w1.y, acc1[5]);
                acc0[6] = fmaf(a_, w1.z, acc0[6]);  acc1[6] = fmaf(b_, w1.z, acc1[6]);
                acc0[7] = fmaf(a_, w1.w, acc0[7]);  acc1[7] = fmaf(b_, w1.w, acc1[7]);
            }
        }
        __syncthreads();
    }

    #pragma unroll
    for (int e = 0; e < 8; ++e) {
        const float be = bias[wv * 8 + e];
        lt[lane][wv * 8 + e]      = acc0[e] + be;
        lt[64 + lane][wv * 8 + e] = acc1[e] + be;
    }
    __syncthreads();

    // softmax + z-loss: waves 0,1 — one token per lane (math verbatim R2)
    if (tid < TBLK) {
        float v[E];
        float m = -1e30f;
        #pragma unroll
        for (int e = 0; e < E; ++e) { v[e] = lt[tid][e]; m = fmaxf(m, v[e]); }
        float s = 0.f;
        #pragma unroll
        for (int e = 0; e < E; ++e) { v[e] = expf(v[e] - m); s += v[e]; }
        const float inv = 1.f / s;
        #pragma unroll
        for (int e = 0; e < E; ++e) lt[tid][e] = v[e] * inv;
        const float lz = m + logf(s);
        float zsq = lz * lz;
        #pragma unroll
        for (int off = 32; off; off >>= 1) zsq += __shfl_down(zsq, off, 64);
        if ((tid & 63) == 0) atomicAdd(z_out, zsq * (1.0f / (float)NTOK));
    }
    __syncthreads();

    // store probs transposed: probs_t[(g*E+e)*T + t], 128 tokens per block
    const int g  = blk >> 5;           // 32 blocks per group
    const int tb = (blk & 31) * TBLK;
    #pragma unroll
    for (int j = 0; j < 8; ++j) {
        const int e = wv * 8 + j;
        float* __restrict__ col = probs_t + ((size_t)(g * E + e)) * T + tb;
        col[lane]      = lt[lane][e];
        col[64 + lane] = lt[64 + lane][e];
    }
}

// ---------------------------------------------------------------------------
// Kernel 2: per-(g,e) top-64 via threshold + compact + rank-by-count.
// VERBATIM R10 (estimated cheap after the R3 decomposition; exact
// jax.lax.top_k semantics, harness-proven absmax 0.0).
// ---------------------------------------------------------------------------
__global__ __launch_bounds__(256) void k_topk(
    const float* __restrict__ probs_t, float* __restrict__ out)
{
    const int ge   = blockIdx.x;          // g*E + e
    const int g    = ge >> 5;
    const int e    = ge & 31;
    const int tid  = threadIdx.x;
    const int lane = tid & 63;
    const int wv   = tid >> 6;
    const float* __restrict__ col = probs_t + (size_t)ge * T;

    __shared__ unsigned long long sk[T];   // worst-case all survive: 32 KB
    __shared__ unsigned long long wmin[4];
    __shared__ unsigned long long thr_s;
    __shared__ int cnt;

    if (tid == 0) cnt = 0;

    // ---- load 16 keys/thread (coalesced: t = j*256 + tid)
    unsigned long long keys[16];
    #pragma unroll
    for (int j = 0; j < 16; ++j) {
        const int t = j * 256 + tid;
        unsigned u = __float_as_uint(col[t]);
        u = (u & 0x80000000u) ? ~u : (u | 0x80000000u);
        keys[j] = ((unsigned long long)u << 32) | (unsigned)(4095 - t);
    }

    // ---- threshold: min over 64 group-of-4-thread maxima (64 elems/group)
    unsigned long long tm = keys[0];
    #pragma unroll
    for (int j = 1; j < 16; ++j) tm = (keys[j] > tm) ? keys[j] : tm;
    unsigned long long gm = tm;
    {
        unsigned long long o = __shfl_xor(gm, 1, 64); gm = (o > gm) ? o : gm;
        o = __shfl_xor(gm, 2, 64);                    gm = (o > gm) ? o : gm;
    }
    unsigned long long mn = gm;
    #pragma unroll
    for (int off = 4; off < 64; off <<= 1) {
        const unsigned long long o = __shfl_xor(mn, off, 64);
        mn = (o < mn) ? o : mn;
    }
    if (lane == 0) wmin[wv] = mn;
    __syncthreads();
    if (tid == 0) {
        unsigned long long m = wmin[0];
        #pragma unroll
        for (int w = 1; w < 4; ++w) m = (wmin[w] < m) ? wmin[w] : m;
        thr_s = m;
    }
    __syncthreads();
    const unsigned long long thr = thr_s;

    // ---- ballot-compact survivors (key >= thr) into sk[]
    #pragma unroll
    for (int j = 0; j < 16; ++j) {
        const bool pred = (keys[j] >= thr);
        const unsigned long long mask = __ballot(pred);
        int base = 0;
        if (lane == 0) {
            const int nw = (int)__popcll(mask);
            base = nw ? atomicAdd(&cnt, nw) : 0;
        }
        base = __shfl(base, 0, 64);
        if (pred) {
            const int pos = (int)__popcll(mask & ((1ull << lane) - 1ull));
            sk[base + pos] = keys[j];
        }
    }
    __syncthreads();
    const int n = cnt;

    // ---- rank-by-count over survivors (uniform j -> LDS broadcast reads)
    for (int i = tid; i < n; i += 256) {
        const unsigned long long k = sk[i];
        int r = 0;
        for (int j = 0; j < n; ++j) r += (sk[j] > k) ? 1 : 0;
        if (r < C) {
            const int t = 4095 - (int)(k & 0xFFFFFFFFu);
            const unsigned mu   = (unsigned)(k >> 32);
            const unsigned orig = (mu & 0x80000000u) ? (mu & 0x7FFFFFFFu) : ~mu;
            const size_t idx = ((((size_t)g * T + t) * E + e) * C + r);
            out[idx] = __uint_as_float(orig);    // combine = gate
            out[idx + COMBINE_SZ] = 1.0f;        // dispatch mask
        }
    }
}

// ---------------------------------------------------------------------------
extern "C" void kernel_launch(void* const* d_in, const int* in_sizes, int n_in,
                              void* d_out, int out_size, void* d_ws, size_t ws_size,
                              hipStream_t stream) {
    const float* x = (const float*)d_in[0];   // [G,T,H]
    const float* W = (const float*)d_in[1];   // [H,E]
    const float* b = (const float*)d_in[2];   // [E]
    float* out     = (float*)d_out;           // combine | dispatch | z_loss
    float* probs_t = (float*)d_ws;            // [G*E, T] = 4 MB scratch

    // R11: custom zero-fill kernel instead of hipMemsetAsync (which ran at
    // ~1.5-2 TB/s on our 536.9 MB region per R3 forensics).
    k_zero<<<2048, 256, 0, stream>>>(out);

    k_router<<<NTOK / TBLK, 256, 0, stream>>>(x, W, b, probs_t, out + 2 * COMBINE_SZ);
    k_topk<<<G * E, 256, 0, stream>>>(probs_t, out);
}